// Round 1
// baseline (745.654 us; speedup 1.0000x reference)
//
#include <hip/hip_runtime.h>
#include <hip/hip_bf16.h>

// Problem constants
#define BQ 1024
#define DIMD 256
#define MKEYS 100000
#define TOPK 32
#define NTILES 6250        // MKEYS / 16
#define NSUPER 3125        // MKEYS / 32

typedef __attribute__((ext_vector_type(8))) short bf16x8;
typedef __attribute__((ext_vector_type(4))) float f32x4;

#define MFMA_16x16x32(a, b, c) __builtin_amdgcn_mfma_f32_16x16x32_bf16(a, b, c, 0, 0, 0)

__device__ __forceinline__ bf16x8 pack8(const float4& x, const float4& y) {
    bf16x8 r;
    r[0] = __builtin_bit_cast(short, __float2bfloat16(x.x));
    r[1] = __builtin_bit_cast(short, __float2bfloat16(x.y));
    r[2] = __builtin_bit_cast(short, __float2bfloat16(x.z));
    r[3] = __builtin_bit_cast(short, __float2bfloat16(x.w));
    r[4] = __builtin_bit_cast(short, __float2bfloat16(y.x));
    r[5] = __builtin_bit_cast(short, __float2bfloat16(y.y));
    r[6] = __builtin_bit_cast(short, __float2bfloat16(y.z));
    r[7] = __builtin_bit_cast(short, __float2bfloat16(y.w));
    return r;
}

// ---------------------------------------------------------------------------
// qt = query @ W_q  (fp32) ; also emit bf16 copy for the MFMA retrieval GEMM.
// One block per batch row; W_q stays L2-resident.
__global__ __launch_bounds__(256) void k_qt(const float* __restrict__ query,
                                            const float* __restrict__ Wq,
                                            float* __restrict__ qt,
                                            __hip_bfloat16* __restrict__ qtb) {
    __shared__ float qrow[DIMD];
    const int b = blockIdx.x, t = threadIdx.x;
    qrow[t] = query[b * DIMD + t];
    __syncthreads();
    float acc = 0.f;
#pragma unroll 4
    for (int k = 0; k < DIMD; ++k)
        acc = fmaf(qrow[k], Wq[k * DIMD + t], acc);  // coalesced across t
    qt[b * DIMD + t] = acc;
    qtb[b * DIMD + t] = __float2bfloat16(acc);
}

// ---------------------------------------------------------------------------
// kn = mem_keys / max(||row||, eps) as bf16, plus fp32 inv-norm per key.
// 4 rows per block, one wave per row, float4 loads.
__global__ __launch_bounds__(256) void k_kn(const float* __restrict__ keys,
                                            __hip_bfloat16* __restrict__ knb,
                                            float* __restrict__ invn) {
    const int wv = threadIdx.x >> 6, lane = threadIdx.x & 63;
    const int row = blockIdx.x * 4 + wv;
    const float4 v = *(const float4*)(keys + (size_t)row * DIMD + lane * 4);
    float ss = v.x * v.x + v.y * v.y + v.z * v.z + v.w * v.w;
#pragma unroll
    for (int m = 1; m < 64; m <<= 1) ss += __shfl_xor(ss, m);
    const float inv = 1.0f / fmaxf(sqrtf(ss), 1e-8f);
    ushort4 u;
    u.x = (unsigned short)__builtin_bit_cast(short, __float2bfloat16(v.x * inv));
    u.y = (unsigned short)__builtin_bit_cast(short, __float2bfloat16(v.y * inv));
    u.z = (unsigned short)__builtin_bit_cast(short, __float2bfloat16(v.z * inv));
    u.w = (unsigned short)__builtin_bit_cast(short, __float2bfloat16(v.w * inv));
    *(ushort4*)((unsigned short*)knb + (size_t)row * DIMD + lane * 4) = u;
    if (lane == 0) invn[row] = inv;
}

// ---------------------------------------------------------------------------
// sims = qt_bf16 @ kn_bf16^T   (bf16 MFMA, fp32 accum), fused per-16-key-tile
// fp32 row maxima for the selection threshold.
// grid: (512 key-chunks, slab_rows/128). Block = 4 waves; wave owns 32 q-rows
// (2 sub-tiles of 16); all waves share key tiles via L1.
__global__ __launch_bounds__(256) void k_sims(const __hip_bfloat16* __restrict__ qtb,
                                              const __hip_bfloat16* __restrict__ knb,
                                              __hip_bfloat16* __restrict__ sims,  // [S, MKEYS]
                                              float* __restrict__ tmax,           // [S, NTILES]
                                              int slab_base) {
    const int lane = threadIdx.x & 63;
    const int wv = threadIdx.x >> 6;
    const int col = lane & 15;
    const int quad = lane >> 4;
    const int rloc_base = blockIdx.y * 128 + wv * 32;

    // A fragments: A[m = lane&15][k = quad*8 + j], K split into 8 steps of 32
    bf16x8 afr[2][8];
#pragma unroll
    for (int sub = 0; sub < 2; ++sub) {
        const short* ap = (const short*)qtb + (size_t)(slab_base + rloc_base + sub * 16 + col) * DIMD;
#pragma unroll
        for (int kk = 0; kk < 8; ++kk)
            afr[sub][kk] = *(const bf16x8*)(ap + kk * 32 + quad * 8);
    }

    const int st0 = (int)(((long)blockIdx.x * NSUPER) >> 9);
    const int st1 = (int)(((long)(blockIdx.x + 1) * NSUPER) >> 9);

    for (int st = st0; st < st1; ++st) {
        const int c0 = st * 32;  // 32 keys: two 16-key tiles
        f32x4 acc[2][2];
#pragma unroll
        for (int i = 0; i < 2; ++i)
#pragma unroll
            for (int j = 0; j < 2; ++j) { acc[i][j][0] = 0.f; acc[i][j][1] = 0.f; acc[i][j][2] = 0.f; acc[i][j][3] = 0.f; }

#pragma unroll
        for (int kk = 0; kk < 8; ++kk) {
            // B[k][n]: n = lane&15 (key), k = quad*8 + j (dim) -> contiguous 16B
            const short* bp = (const short*)knb + kk * 32 + quad * 8;
            bf16x8 b0 = *(const bf16x8*)(bp + (size_t)(c0 + col) * DIMD);
            bf16x8 b1 = *(const bf16x8*)(bp + (size_t)(c0 + 16 + col) * DIMD);
            acc[0][0] = MFMA_16x16x32(afr[0][kk], b0, acc[0][0]);
            acc[1][0] = MFMA_16x16x32(afr[1][kk], b0, acc[1][0]);
            acc[0][1] = MFMA_16x16x32(afr[0][kk], b1, acc[0][1]);
            acc[1][1] = MFMA_16x16x32(afr[1][kk], b1, acc[1][1]);
        }

        // epilogue: bf16 store + fp32 tile-max (C layout: col=lane&15, row=quad*4+reg)
#pragma unroll
        for (int sub = 0; sub < 2; ++sub) {
#pragma unroll
            for (int kt = 0; kt < 2; ++kt) {
                f32x4 a = acc[sub][kt];
                const int rl = rloc_base + sub * 16 + quad * 4;
                const int cc = c0 + kt * 16 + col;
#pragma unroll
                for (int reg = 0; reg < 4; ++reg)
                    sims[(size_t)(rl + reg) * MKEYS + cc] = __float2bfloat16(a[reg]);
                // max over the 16 columns (lanes within the quad group)
#pragma unroll
                for (int m = 1; m <= 8; m <<= 1) {
                    a[0] = fmaxf(a[0], __shfl_xor(a[0], m));
                    a[1] = fmaxf(a[1], __shfl_xor(a[1], m));
                    a[2] = fmaxf(a[2], __shfl_xor(a[2], m));
                    a[3] = fmaxf(a[3], __shfl_xor(a[3], m));
                }
                if (col == 0) {
                    const int tile = st * 2 + kt;
#pragma unroll
                    for (int reg = 0; reg < 4; ++reg)
                        tmax[(size_t)(rl + reg) * NTILES + tile] = a[reg];
                }
            }
        }
    }
}

// ---------------------------------------------------------------------------
// Per-row exact top-32: tau = 40th-largest per-thread tile-max (a valid lower
// bound: >=40 distinct tiles each contribute a key >= tau), collect candidate
// keys from selected tiles (bf16 compare with rounding guard), rescore them in
// exact fp32 against mem_keys, then pick top-32.
__global__ __launch_bounds__(256) void k_select(const float* __restrict__ tmax,
                                                const __hip_bfloat16* __restrict__ sims,
                                                const float* __restrict__ qt,
                                                const float* __restrict__ keys,
                                                const float* __restrict__ invn,
                                                int* __restrict__ topk,
                                                int slab_base) {
    __shared__ float smax[NTILES];
    __shared__ float qs[DIMD];
    __shared__ float thrmax[256];
    __shared__ int tsel[1024];
    __shared__ int cidx[1024];
    __shared__ float cval[1024];
    __shared__ int nsel, ncand;
    __shared__ float tauS;

    const int t = threadIdx.x;
    const int rl = blockIdx.x;
    const int gr = slab_base + rl;

    qs[t] = qt[gr * DIMD + t];
    float lm = -1e30f;
    for (int i = t; i < NTILES; i += 256) {
        float v = tmax[(size_t)rl * NTILES + i];
        smax[i] = v;
        lm = fmaxf(lm, v);
    }
    thrmax[t] = lm;
    if (t == 0) { nsel = 0; ncand = 0; }
    __syncthreads();

    // wave 0: 40th largest of the 256 thread maxima (ties removed together ->
    // tau only gets smaller, which stays valid).
    if (t < 64) {
        float v0 = thrmax[t], v1 = thrmax[t + 64], v2 = thrmax[t + 128], v3 = thrmax[t + 192];
        float tau = -1e30f;
        for (int it = 0; it < 40; ++it) {
            float lmx = fmaxf(fmaxf(v0, v1), fmaxf(v2, v3));
            float m = lmx;
#pragma unroll
            for (int off = 1; off < 64; off <<= 1) m = fmaxf(m, __shfl_xor(m, off));
            if (lmx == m) {
                if (v0 == m) v0 = -1e30f;
                else if (v1 == m) v1 = -1e30f;
                else if (v2 == m) v2 = -1e30f;
                else v3 = -1e30f;
            }
            tau = m;
        }
        if (t == 0) tauS = tau;
    }
    __syncthreads();
    const float tau = tauS;

    // tiles whose fp32 max >= tau
    for (int i = t; i < NTILES; i += 256)
        if (smax[i] >= tau) {
            int p = atomicAdd(&nsel, 1);
            if (p < 1024) tsel[p] = i;
        }
    __syncthreads();
    const int ns = min(nsel, 1024);
    // guard for bf16 storage rounding (rel err <= 2^-8)
    const float tadj = tau - fabsf(tau) * 0.015f - 1e-5f;

    for (int i = t >> 4; i < ns; i += 16) {
        const int key = tsel[i] * 16 + (t & 15);
        const float v = __bfloat162float(sims[(size_t)rl * MKEYS + key]);
        if (v >= tadj) {
            int p = atomicAdd(&ncand, 1);
            if (p < 1024) cidx[p] = key;
        }
    }
    __syncthreads();
    const int nc = min(ncand, 1024);

    // exact fp32 rescore (ranking identical to reference up to fp32 rounding)
    for (int c = t; c < nc; c += 256) {
        const int key = cidx[c];
        const float4* kp = (const float4*)(keys + (size_t)key * DIMD);
        float s0 = 0.f, s1 = 0.f, s2 = 0.f, s3 = 0.f;
#pragma unroll 8
        for (int j = 0; j < 64; ++j) {
            float4 kv = kp[j];
            s0 = fmaf(qs[j * 4 + 0], kv.x, s0);
            s1 = fmaf(qs[j * 4 + 1], kv.y, s1);
            s2 = fmaf(qs[j * 4 + 2], kv.z, s2);
            s3 = fmaf(qs[j * 4 + 3], kv.w, s3);
        }
        cval[c] = ((s0 + s1) + (s2 + s3)) * invn[key];
    }
    __syncthreads();

    // wave 0: top-32 by repeated argmax over <=1024 candidates in registers
    if (t < 64) {
        float cv[16];
        int ci[16];
#pragma unroll
        for (int i = 0; i < 16; ++i) {
            int c = t + i * 64;
            cv[i] = (c < nc) ? cval[c] : -1e30f;
            ci[i] = (c < nc) ? cidx[c] : 0;
        }
        for (int it = 0; it < TOPK; ++it) {
            float lmx = -1e30f;
            int li = 0;
#pragma unroll
            for (int i = 0; i < 16; ++i)
                if (cv[i] > lmx) { lmx = cv[i]; li = i; }
            float m = lmx;
            int mi = ci[li];
            int src = t;
#pragma unroll
            for (int off = 1; off < 64; off <<= 1) {
                float om = __shfl_xor(m, off);
                int omi = __shfl_xor(mi, off);
                int osrc = __shfl_xor(src, off);
                if (om > m || (om == m && osrc < src)) { m = om; mi = omi; src = osrc; }
            }
            if (t == src) cv[li] = -1e30f;
            if (t == 0) topk[gr * TOPK + it] = (mi >= 0 && mi < MKEYS) ? mi : 0;
        }
    }
}

// ---------------------------------------------------------------------------
// k = gather(mem_keys, idx) @ Wk^T + bk ; v likewise with mem_values/Wv/bv.
// bf16 MFMA, fp32 weights/inputs cast on the fly. Block = 32 rows of the
// flat [B*K, D] gather; 4 waves = 4 column groups of 64.
__global__ __launch_bounds__(256) void k_proj(const float* __restrict__ mem_keys,
                                              const float* __restrict__ mem_values,
                                              const float* __restrict__ in_w,
                                              const float* __restrict__ in_b,
                                              const int* __restrict__ topk,
                                              __hip_bfloat16* __restrict__ kb,
                                              __hip_bfloat16* __restrict__ vb) {
    const int lane = threadIdx.x & 63;
    const int wv = threadIdx.x >> 6;
    const int col = lane & 15, quad = lane >> 4;
    const int rbase = blockIdx.x * 32;

#pragma unroll
    for (int phase = 0; phase < 2; ++phase) {
        const float* src = phase ? mem_values : mem_keys;
        const float* W = in_w + (phase ? 2 * DIMD * DIMD : DIMD * DIMD);
        const float* bias = in_b + (phase ? 2 * DIMD : DIMD);
        __hip_bfloat16* dst = phase ? vb : kb;

        bf16x8 afr[2][8];
#pragma unroll
        for (int sub = 0; sub < 2; ++sub) {
            int r = rbase + sub * 16 + col;
            int key = topk[r];
            key = (key >= 0 && key < MKEYS) ? key : 0;
            const float* ap = src + (size_t)key * DIMD;
#pragma unroll
            for (int kk = 0; kk < 8; ++kk) {
                float4 x = *(const float4*)(ap + kk * 32 + quad * 8);
                float4 y = *(const float4*)(ap + kk * 32 + quad * 8 + 4);
                afr[sub][kk] = pack8(x, y);
            }
        }

        const int o0 = wv * 64;
#pragma unroll
        for (int ct = 0; ct < 4; ++ct) {
            const int oc = o0 + ct * 16;
            f32x4 a0, a1;
            a0[0] = a0[1] = a0[2] = a0[3] = 0.f;
            a1[0] = a1[1] = a1[2] = a1[3] = 0.f;
            const float* wp = W + (size_t)(oc + col) * DIMD;
#pragma unroll
            for (int kk = 0; kk < 8; ++kk) {
                float4 x = *(const float4*)(wp + kk * 32 + quad * 8);
                float4 y = *(const float4*)(wp + kk * 32 + quad * 8 + 4);
                bf16x8 bfr = pack8(x, y);
                a0 = MFMA_16x16x32(afr[0][kk], bfr, a0);
                a1 = MFMA_16x16x32(afr[1][kk], bfr, a1);
            }
            const float bia = bias[oc + col];
#pragma unroll
            for (int reg = 0; reg < 4; ++reg) {
                dst[(size_t)(rbase + quad * 4 + reg) * DIMD + oc + col] = __float2bfloat16(a0[reg] + bia);
                dst[(size_t)(rbase + 16 + quad * 4 + reg) * DIMD + oc + col] = __float2bfloat16(a1[reg] + bia);
            }
        }
    }
}

// ---------------------------------------------------------------------------
// Per batch row: q-projection, 4-head attention over 32 keys, out-projection.
__global__ __launch_bounds__(256) void k_attn(const float* __restrict__ qt,
                                              const __hip_bfloat16* __restrict__ kb,
                                              const __hip_bfloat16* __restrict__ vb,
                                              const float* __restrict__ in_w,
                                              const float* __restrict__ in_b,
                                              const float* __restrict__ ow,
                                              const float* __restrict__ ob,
                                              float* __restrict__ out) {
    __shared__ float qs[DIMD], qv[DIMD], sc[128], at[128], ao[DIMD];
    const int b = blockIdx.x, t = threadIdx.x;
    qs[t] = qt[b * DIMD + t];
    __syncthreads();
    {
        float acc = in_b[t];
        const float* wrow = in_w + (size_t)t * DIMD;  // Wq rows 0..255
#pragma unroll 4
        for (int d = 0; d < DIMD; ++d) acc = fmaf(qs[d], wrow[d], acc);
        qv[t] = acc;
    }
    __syncthreads();
    if (t < 128) {
        const int h = t >> 5, s = t & 31;
        const __hip_bfloat16* kr = kb + (size_t)(b * TOPK + s) * DIMD + h * 64;
        float acc = 0.f;
#pragma unroll 4
        for (int d = 0; d < 64; ++d) acc = fmaf(qv[h * 64 + d], __bfloat162float(kr[d]), acc);
        sc[t] = acc * 0.125f;  // 1/sqrt(64)
    }
    __syncthreads();
    if (t < 4) {
        float mx = -1e30f;
        for (int s = 0; s < TOPK; ++s) mx = fmaxf(mx, sc[t * 32 + s]);
        float sum = 0.f;
        for (int s = 0; s < TOPK; ++s) {
            float e = __expf(sc[t * 32 + s] - mx);
            at[t * 32 + s] = e;
            sum += e;
        }
        const float inv = 1.0f / sum;
        for (int s = 0; s < TOPK; ++s) at[t * 32 + s] *= inv;
    }
    __syncthreads();
    {
        const int h = t >> 6;
        const __hip_bfloat16* vr = vb + (size_t)(b * TOPK) * DIMD + t;
        float acc = 0.f;
#pragma unroll
        for (int s = 0; s < TOPK; ++s) acc = fmaf(at[h * 32 + s], __bfloat162float(vr[(size_t)s * DIMD]), acc);
        ao[t] = acc;
    }
    __syncthreads();
    {
        float acc = ob[t];
        const float* wrow = ow + (size_t)t * DIMD;
#pragma unroll 4
        for (int d = 0; d < DIMD; ++d) acc = fmaf(ao[d], wrow[d], acc);
        out[(size_t)b * DIMD + t] = acc;
    }
}

// ---------------------------------------------------------------------------
extern "C" void kernel_launch(void* const* d_in, const int* in_sizes, int n_in,
                              void* d_out, int out_size, void* d_ws, size_t ws_size,
                              hipStream_t stream) {
    const float* query = (const float*)d_in[0];
    const float* mem_keys = (const float*)d_in[1];
    const float* mem_values = (const float*)d_in[2];
    const float* Wq = (const float*)d_in[3];
    const float* in_w = (const float*)d_in[4];
    const float* in_b = (const float*)d_in[5];
    const float* ow = (const float*)d_in[6];
    const float* ob = (const float*)d_in[7];
    float* out = (float*)d_out;

    char* ws = (char*)d_ws;
    size_t off = 0;
    auto alloc = [&](size_t bytes) -> void* {
        void* p = ws + off;
        off = (off + bytes + 255) & ~(size_t)255;
        return p;
    };
    __hip_bfloat16* knb = (__hip_bfloat16*)alloc((size_t)MKEYS * DIMD * 2);
    float* invn = (float*)alloc((size_t)MKEYS * 4);
    float* qt = (float*)alloc((size_t)BQ * DIMD * 4);
    __hip_bfloat16* qtb = (__hip_bfloat16*)alloc((size_t)BQ * DIMD * 2);
    int* topk = (int*)alloc((size_t)BQ * TOPK * 4);
    __hip_bfloat16* kb = (__hip_bfloat16*)alloc((size_t)BQ * TOPK * DIMD * 2);
    __hip_bfloat16* vb = (__hip_bfloat16*)alloc((size_t)BQ * TOPK * DIMD * 2);

    // slab sizing from remaining workspace: per 128 q-rows we need bf16 sims
    // (128 x MKEYS) + fp32 tile maxima (128 x NTILES)
    const size_t per_group = ((size_t)128 * MKEYS * 2) + ((size_t)128 * NTILES * 4) + 1024;
    const size_t rem = (ws_size > off) ? (ws_size - off) : 0;
    int sg = (int)(rem / per_group);
    if (sg >= 8) sg = 8;
    else if (sg >= 4) sg = 4;
    else if (sg >= 2) sg = 2;
    else sg = 1;  // needs ~116 MB total workspace
    const int S = sg * 128;
    __hip_bfloat16* sims = (__hip_bfloat16*)alloc((size_t)S * MKEYS * 2);
    float* tmax = (float*)alloc((size_t)S * NTILES * 4);

    k_qt<<<BQ, 256, 0, stream>>>(query, Wq, qt, qtb);
    k_kn<<<MKEYS / 4, 256, 0, stream>>>(mem_keys, knb, invn);
    for (int base = 0; base < BQ; base += S) {
        dim3 g(512, sg);
        k_sims<<<g, 256, 0, stream>>>(qtb, knb, sims, tmax, base);
        k_select<<<S, 256, 0, stream>>>(tmax, sims, qt, mem_keys, invn, topk, base);
    }
    k_proj<<<BQ * TOPK / 32, 256, 0, stream>>>(mem_keys, mem_values, in_w, in_b, topk, kb, vb);
    k_attn<<<BQ, 256, 0, stream>>>(qt, kb, vb, in_w, in_b, ow, ob, out);
}